// Round 2
// baseline (389.638 us; speedup 1.0000x reference)
//
#include <hip/hip_runtime.h>

typedef float  f32x4 __attribute__((ext_vector_type(4)));
typedef int    i32x4 __attribute__((ext_vector_type(4)));
typedef short  bf16x8 __attribute__((ext_vector_type(8)));
typedef unsigned short ushort_t;

#define D_MODEL 1024
#define NHEADS  16
#define DH      64
#define BATCH   4
#define SEQ     2048
#define ROWS    (BATCH*SEQ)      /* 8192 */
#define KDIM    1024
#define EPS_F   1e-6f

#define CHUNK   64
#define NC      (SEQ/CHUNK)      /* 32 */
#define SUMREC  4160             /* 64*64 KV + 64 ksum floats per (bh,chunk) */

// ---------------- helpers ----------------
__device__ __forceinline__ unsigned f2bf(float f) {
    union { float f; unsigned u; } v; v.f = f;
    unsigned r = v.u + 0x7fffu + ((v.u >> 16) & 1u);
    return (r >> 16) & 0xffffu;
}

// async global->LDS, 16 bytes per lane; lds base must be wave-uniform
__device__ __forceinline__ void gload16(const void* g, void* lds) {
    __builtin_amdgcn_global_load_lds(
        (const __attribute__((address_space(1))) unsigned int*)g,
        (__attribute__((address_space(3))) unsigned int*)lds, 16, 0, 0);
}

// ---------------- cast x + weights to bf16 ----------------
__global__ __launch_bounds__(256) void k_cast(
        const float* __restrict__ x,  const float* __restrict__ Wq,
        const float* __restrict__ Wk, const float* __restrict__ Wv,
        const float* __restrict__ Wo,
        ushort_t* __restrict__ xb, ushort_t* __restrict__ wb, ushort_t* __restrict__ wob) {
    const int NX8 = ROWS*D_MODEL/8;          // groups of 8 floats
    const int NW8 = D_MODEL*D_MODEL/8;
    const int total = NX8 + 4*NW8;
    for (int i = blockIdx.x*blockDim.x + threadIdx.x; i < total;
         i += gridDim.x*blockDim.x) {
        const float* src; ushort_t* dst; int off;
        if (i < NX8) { src = x; dst = xb; off = i; }
        else {
            int j = i - NX8;
            int w = j / NW8; off = j % NW8;
            if      (w == 0) { src = Wq; dst = wb; }
            else if (w == 1) { src = Wk; dst = wb + D_MODEL*D_MODEL; }
            else if (w == 2) { src = Wv; dst = wb + 2*D_MODEL*D_MODEL; }
            else             { src = Wo; dst = wob; }
        }
        f32x4 a = ((const f32x4*)src)[off*2];
        f32x4 b = ((const f32x4*)src)[off*2 + 1];
        i32x4 o;
        o[0] = (int)(f2bf(a[0]) | (f2bf(a[1]) << 16));
        o[1] = (int)(f2bf(a[2]) | (f2bf(a[3]) << 16));
        o[2] = (int)(f2bf(b[0]) | (f2bf(b[1]) << 16));
        o[3] = (int)(f2bf(b[2]) | (f2bf(b[3]) << 16));
        ((i32x4*)dst)[off] = o;
    }
}

// ---------------- rope cos/sin table ----------------
__global__ __launch_bounds__(256) void k_tab(float2* __restrict__ tab) {
    int i = blockIdx.x*blockDim.x + threadIdx.x;       // t*32 + f
    if (i >= SEQ*32) return;
    int t = i >> 5, f = i & 31;
    float inv = powf(10000.0f, -(float)f / 32.0f);
    float ang = (float)t * inv;
    tab[i] = make_float2(cosf(ang), sinf(ang));
}

// ---------------- bf16 MFMA GEMM:  C[i][j] = sum_k A[i][k] * Bw[j][k] ----------------
// MODE 0: fused QKV epilogue (rope+phi on q,k; writes fp32 q/k/v in [B,H,T,dh])
// MODE 1: plain fp32 store to outp[row*D_MODEL + col]
#define BM 128
#define BN 128
#define BKE 64

template<int MODE>
__global__ __launch_bounds__(256, 2) void k_gemm(
        const ushort_t* __restrict__ A, const ushort_t* __restrict__ Bw, int ntn,
        const float2* __restrict__ tab,
        float* __restrict__ qf, float* __restrict__ kf, float* __restrict__ vf,
        float* __restrict__ outp) {
    __shared__ ushort_t As[8][BM][8];   // [kgroup of 8][row][8 elems] : 16 KB
    __shared__ ushort_t Bs[8][BN][8];
    const int tile = blockIdx.x;
    const int tm = tile / ntn, tn = tile % ntn;
    const int im0 = tm * BM, jn0 = tn * BN;
    const int tid  = threadIdx.x;
    const int w    = tid >> 6, lane = tid & 63;
    const int wr   = w >> 1,  wc   = w & 1;
    const int l4   = lane >> 4, l15 = lane & 15;

    f32x4 acc[4][4];
    #pragma unroll
    for (int m = 0; m < 4; ++m)
        #pragma unroll
        for (int n = 0; n < 4; ++n) acc[m][n] = (f32x4){0.f, 0.f, 0.f, 0.f};

    #pragma unroll 1
    for (int k0 = 0; k0 < KDIM; k0 += BKE) {
        __syncthreads();                 // previous iter's LDS reads complete
        #pragma unroll
        for (int sub = 0; sub < 2; ++sub) {
            int kg = 2*w + sub;
            #pragma unroll
            for (int half = 0; half < 2; ++half) {
                int row = half*64 + lane;
                gload16(A  + (size_t)(im0+row)*KDIM + k0 + kg*8, &As[kg][half*64][0]);
                gload16(Bw + (size_t)(jn0+row)*KDIM + k0 + kg*8, &Bs[kg][half*64][0]);
            }
        }
        __syncthreads();                 // drains vmcnt(0): LDS tiles ready
        #pragma unroll
        for (int ks = 0; ks < 2; ++ks) {
            bf16x8 af[4], bf[4];
            #pragma unroll
            for (int m = 0; m < 4; ++m)
                af[m] = *(const bf16x8*)&As[ks*4 + l4][wr*64 + m*16 + l15][0];
            #pragma unroll
            for (int n = 0; n < 4; ++n)
                bf[n] = *(const bf16x8*)&Bs[ks*4 + l4][wc*64 + n*16 + l15][0];
            #pragma unroll
            for (int m = 0; m < 4; ++m)
                #pragma unroll
                for (int n = 0; n < 4; ++n)
                    acc[m][n] = __builtin_amdgcn_mfma_f32_16x16x32_bf16(
                        af[m], bf[n], acc[m][n], 0, 0, 0);
        }
    }

    if (MODE == 0) {
        const int which = jn0 >> 10;              // 0=q 1=k 2=v (uniform per block)
        const int jq    = jn0 & 1023;
        const int h     = (jq >> 6) + wc;         // wave spans exactly one head
        float* dst = (which == 0) ? qf : (which == 1) ? kf : vf;
        #pragma unroll
        for (int m = 0; m < 4; ++m) {
            #pragma unroll
            for (int r = 0; r < 4; ++r) {
                int row = im0 + wr*64 + m*16 + l4*4 + r;
                int b = row >> 11, t = row & 2047;
                size_t obase = (((size_t)(b*NHEADS + h))*SEQ + (size_t)t)*DH;
                if (which < 2) {
                    #pragma unroll
                    for (int n = 0; n < 2; ++n) {
                        int d = n*16 + l15;                    // d < 32 pairs with d+32
                        float2 cs = tab[t*32 + d];
                        float x1 = acc[m][n][r], x2 = acc[m][n+2][r];
                        float y1 = x1*cs.x - x2*cs.y;
                        float y2 = x1*cs.y + x2*cs.x;
                        y1 = (y1 > 0.f) ? (y1 + 1.f) : expf(y1);   // phi = elu+1
                        y2 = (y2 > 0.f) ? (y2 + 1.f) : expf(y2);
                        dst[obase + d]      = y1;
                        dst[obase + d + 32] = y2;
                    }
                } else {
                    #pragma unroll
                    for (int n = 0; n < 4; ++n)
                        dst[obase + n*16 + l15] = acc[m][n][r];
                }
            }
        }
    } else {
        #pragma unroll
        for (int m = 0; m < 4; ++m)
            #pragma unroll
            for (int n = 0; n < 4; ++n)
                #pragma unroll
                for (int r = 0; r < 4; ++r) {
                    int row = im0 + wr*64 + m*16 + l4*4 + r;
                    int col = jn0 + wc*64 + n*16 + l15;
                    outp[(size_t)row*D_MODEL + col] = acc[m][n][r];
                }
    }
}

// ---------------- phase A: per-chunk K_sum and K^T V ----------------
__global__ __launch_bounds__(256) void k_phaseA(
        const float* __restrict__ kf, const float* __restrict__ vf,
        float* __restrict__ sums) {
    __shared__ float Kl[CHUNK*DH];
    __shared__ float Vl[CHUNK*DH];
    const int bh = blockIdx.x / NC, c = blockIdx.x % NC;
    const int tid = threadIdx.x;
    const size_t base = ((size_t)bh*SEQ + (size_t)c*CHUNK)*DH;
    #pragma unroll
    for (int j = 0; j < 4; ++j) {
        ((f32x4*)Kl)[tid*4+j] = *(const f32x4*)(kf + base + tid*16 + j*4);
        ((f32x4*)Vl)[tid*4+j] = *(const f32x4*)(vf + base + tid*16 + j*4);
    }
    __syncthreads();
    const int d = tid >> 2, e0 = (tid & 3)*16;
    float kv[16];
    #pragma unroll
    for (int j = 0; j < 16; ++j) kv[j] = 0.f;
    float ksum = 0.f;
    for (int s = 0; s < CHUNK; ++s) {
        float ks = Kl[s*DH + d];
        ksum += ks;
        #pragma unroll
        for (int j = 0; j < 16; ++j) kv[j] += ks * Vl[s*DH + e0 + j];
    }
    float* op = sums + (size_t)(bh*NC + c)*SUMREC;
    #pragma unroll
    for (int j = 0; j < 16; ++j) op[d*DH + e0 + j] = kv[j];
    if ((tid & 3) == 0) op[4096 + d] = ksum;
}

// ---------------- phase B: exclusive prefix over chunks (in place) ----------------
__global__ __launch_bounds__(256) void k_phaseB(float* __restrict__ sums) {
    const int bh = blockIdx.x;
    const int tid = threadIdx.x;
    f32x4 run[4];
    #pragma unroll
    for (int j = 0; j < 4; ++j) run[j] = (f32x4){0.f, 0.f, 0.f, 0.f};
    float runk = 0.f;
    for (int c = 0; c < NC; ++c) {
        float* p = sums + (size_t)(bh*NC + c)*SUMREC;
        f32x4* pv = (f32x4*)p;
        #pragma unroll
        for (int j = 0; j < 4; ++j) {
            f32x4 t = pv[tid*4 + j];
            pv[tid*4 + j] = run[j];
            run[j] += t;
        }
        if (tid < 64) {
            float t = p[4096 + tid];
            p[4096 + tid] = runk;
            runk += t;
        }
    }
}

// ---------------- phase C: outputs; writes Y as bf16 [B,T,D] ----------------
__global__ __launch_bounds__(256) void k_phaseC(
        const float* __restrict__ qf, const float* __restrict__ kf,
        const float* __restrict__ vf, const float* __restrict__ sums,
        ushort_t* __restrict__ Yb) {
    __shared__ float Kl[CHUNK*DH];
    __shared__ float Vl[CHUNK*DH];
    __shared__ float KVp[DH*DH];
    __shared__ float Ksp[DH];
    const int bh = blockIdx.x / NC, c = blockIdx.x % NC;
    const int b = bh >> 4, h = bh & 15;
    const int tid = threadIdx.x;
    const int lane = tid & 63;
    const size_t base = ((size_t)bh*SEQ + (size_t)c*CHUNK)*DH;
    {
        const float* sp = sums + (size_t)(bh*NC + c)*SUMREC;
        #pragma unroll
        for (int j = 0; j < 4; ++j) {
            ((f32x4*)Kl)[tid*4+j]  = *(const f32x4*)(kf + base + tid*16 + j*4);
            ((f32x4*)Vl)[tid*4+j]  = *(const f32x4*)(vf + base + tid*16 + j*4);
            ((f32x4*)KVp)[tid*4+j] = ((const f32x4*)sp)[tid*4+j];
        }
        if (tid < 64) Ksp[tid] = sp[4096 + tid];
    }
    __syncthreads();
    const int tl = tid >> 2;             // local time 0..63
    const int g0 = tid & 3;
    const int d0 = g0*16, e0 = g0*16;
    float q[16];
    #pragma unroll
    for (int j = 0; j < 4; ++j)
        *(f32x4*)&q[j*4] = *(const f32x4*)(qf + base + (size_t)tl*DH + d0 + j*4);
    float y[16];
    #pragma unroll
    for (int j = 0; j < 16; ++j) y[j] = 0.f;
    float den;
    {   // den_inter = q . Ksum_prev  (split over 4 teammates, shuffle-reduced)
        float dp = 0.f;
        #pragma unroll
        for (int j = 0; j < 16; ++j) dp += q[j]*Ksp[d0+j];
        dp += __shfl_xor(dp, 1);
        dp += __shfl_xor(dp, 2);
        den = dp;
    }
    // y_inter = q_full @ KV_prev  (full q gathered via 4-lane shuffles)
    #pragma unroll
    for (int dj = 0; dj < 16; ++dj) {
        #pragma unroll
        for (int g = 0; g < 4; ++g) {
            float qd = __shfl(q[dj], (lane & ~3) | g, 64);
            int dr = g*16 + dj;
            #pragma unroll
            for (int j = 0; j < 16; ++j) y[j] += qd * KVp[dr*DH + e0 + j];
        }
    }
    // intra-chunk causal part
    for (int s = 0; s < CHUNK; ++s) {
        float wp = 0.f;
        #pragma unroll
        for (int j = 0; j < 16; ++j) wp += q[j]*Kl[s*DH + d0 + j];
        wp += __shfl_xor(wp, 1);
        wp += __shfl_xor(wp, 2);
        if (s <= tl) {
            den += wp;
            #pragma unroll
            for (int j = 0; j < 16; ++j) y[j] += wp * Vl[s*DH + e0 + j];
        }
    }
    den = fmaxf(den, EPS_F);
    float inv = 1.f / den;
    const int t = c*CHUNK + tl;
    const size_t yoff = ((size_t)b*SEQ + t)*D_MODEL + h*DH + e0;
    i32x4 o0, o1;
    #pragma unroll
    for (int j = 0; j < 4; ++j) {
        o0[j] = (int)(f2bf(y[2*j]*inv)     | (f2bf(y[2*j+1]*inv)   << 16));
        o1[j] = (int)(f2bf(y[8+2*j]*inv)   | (f2bf(y[9+2*j]*inv)   << 16));
    }
    *(i32x4*)(Yb + yoff)     = o0;
    *(i32x4*)(Yb + yoff + 8) = o1;
}

// ---------------- launcher ----------------
extern "C" void kernel_launch(void* const* d_in, const int* in_sizes, int n_in,
                              void* d_out, int out_size, void* d_ws, size_t ws_size,
                              hipStream_t stream) {
    const float* x  = (const float*)d_in[0];
    const float* Wq = (const float*)d_in[1];
    const float* Wk = (const float*)d_in[2];
    const float* Wv = (const float*)d_in[3];
    const float* Wo = (const float*)d_in[4];

    char* p = (char*)d_ws;
    auto carve = [&](size_t bytes) -> char* {
        char* r = p; p += (bytes + 255) & ~(size_t)255; return r;
    };
    float2*   tab  = (float2*)  carve((size_t)SEQ*32*sizeof(float2));
    ushort_t* xb   = (ushort_t*)carve((size_t)ROWS*D_MODEL*2);
    ushort_t* wb   = (ushort_t*)carve((size_t)3*D_MODEL*D_MODEL*2);
    ushort_t* wob  = (ushort_t*)carve((size_t)D_MODEL*D_MODEL*2);
    float*    qf   = (float*)   carve((size_t)ROWS*D_MODEL*4);
    float*    kf   = (float*)   carve((size_t)ROWS*D_MODEL*4);
    float*    vf   = (float*)   carve((size_t)ROWS*D_MODEL*4);
    float*    sums = (float*)   carve((size_t)BATCH*NHEADS*NC*SUMREC*4);
    ushort_t* Yb   = (ushort_t*)carve((size_t)ROWS*D_MODEL*2);
    (void)ws_size; (void)in_sizes; (void)n_in; (void)out_size;

    k_cast<<<2048, 256, 0, stream>>>(x, Wq, Wk, Wv, Wo, xb, wb, wob);
    k_tab <<<SEQ*32/256, 256, 0, stream>>>(tab);
    k_gemm<0><<<(ROWS/BM)*(3*D_MODEL/BN), 256, 0, stream>>>(
        xb, wb, 3*D_MODEL/BN, tab, qf, kf, vf, nullptr);
    k_phaseA<<<BATCH*NHEADS*NC, 256, 0, stream>>>(kf, vf, sums);
    k_phaseB<<<BATCH*NHEADS, 256, 0, stream>>>(sums);
    k_phaseC<<<BATCH*NHEADS*NC, 256, 0, stream>>>(qf, kf, vf, sums, Yb);
    k_gemm<1><<<(ROWS/BM)*(D_MODEL/BN), 256, 0, stream>>>(
        Yb, wob, D_MODEL/BN, nullptr, nullptr, nullptr, nullptr, (float*)d_out);
}